// Round 2
// baseline (232.135 us; speedup 1.0000x reference)
//
#include <hip/hip_runtime.h>

// TeacherEmbeddingTransform: block-diagonal GEMM, fp32.
//   x: (16384, 2304), weight: (25600,1) flat, bias: (576,), out: (16384, 576)
//   Blocks: 16x [16->4], 32x [32->8], 16x [64->16]
// Memory-bound: 151 MB read + 38 MB write => ~30 us floor at 6.3 TB/s.
//
// v2 (resubmit — R1 bench was an infra failure, no counters returned):
//   4x4 micro-tile + sparsity-specialized k-loops.
//   - 36 chunks of 64 in-cols -> 16 out-cols each (4x 16->4 | 2x 32->8 | 1x 64->16)
//   - wg = 128 thr (2 waves), 128 rows, one chunk. Per wave: the full 64x16
//     output tile; lane (rq=lane&15, cq=lane>>4) owns rows {rq,rq+16,rq+32,rq+48}
//     x cols 4cq..4cq+3. Row stride 16 keeps XS_LDW=68's 4-dword bank step
//     (2-way = free) and 16B alignment for ds_read_b128.
//   - per k-quad: 4 x b128 + 4 w b128 -> 64 FMA (8 FMA/read vs 3.2 in v1),
//     and the x tile is read from LDS once per wave instead of 4x.
//   - lane's 4 cols live in ONE diagonal block -> k-loop only spans that
//     block: 4 iters (g1), 8 (g2), 16 (g3). Kills the 31% zero-padded FMAs
//     and the matching x-reads of the dense-64k scheme.
//   - LDS 38.9 KB -> 4 wg/CU (8 waves/CU), staging of one wg overlaps
//     compute of its CU neighbors.
// Budget/CU: LDS ~11 us, FMA ~5 us, HBM ~30 us -> HBM-bound ~33 us.

#define BATCH   16384
#define IN_DIM  2304
#define OUT_DIM 576
#define CHUNKS  36
#define XS_LDW  68   // 64 + 4 pad; row step = 4 banks -> strided-row b128 is 2-way (free)
#define ROWS_WG 128

#define FMA_ROW(A, X)                                       \
    A.x += X.x*w0.x + X.y*w1.x + X.z*w2.x + X.w*w3.x;       \
    A.y += X.x*w0.y + X.y*w1.y + X.z*w2.y + X.w*w3.y;       \
    A.z += X.x*w0.z + X.y*w1.z + X.z*w2.z + X.w*w3.z;       \
    A.w += X.x*w0.w + X.y*w1.w + X.z*w2.w + X.w*w3.w;

template<int NT>
__device__ __forceinline__ void tile_fma(
    const float* xq0, const float* xq1, const float* xq2, const float* xq3,
    const float* wq, float4& a0, float4& a1, float4& a2, float4& a3)
{
#pragma unroll
    for (int t = 0; t < NT; ++t) {
        const int k = t << 2;
        const float4 x0 = *reinterpret_cast<const float4*>(xq0 + k);
        const float4 x1 = *reinterpret_cast<const float4*>(xq1 + k);
        const float4 x2 = *reinterpret_cast<const float4*>(xq2 + k);
        const float4 x3 = *reinterpret_cast<const float4*>(xq3 + k);
        const float4 w0 = *reinterpret_cast<const float4*>(wq + (k + 0) * 16);
        const float4 w1 = *reinterpret_cast<const float4*>(wq + (k + 1) * 16);
        const float4 w2 = *reinterpret_cast<const float4*>(wq + (k + 2) * 16);
        const float4 w3 = *reinterpret_cast<const float4*>(wq + (k + 3) * 16);
        FMA_ROW(a0, x0)
        FMA_ROW(a1, x1)
        FMA_ROW(a2, x2)
        FMA_ROW(a3, x3)
    }
}

__global__ __launch_bounds__(128) void fused_block_mm(
    const float* __restrict__ x, const float* __restrict__ w,
    const float* __restrict__ bias, float* __restrict__ out)
{
    __shared__ float xs[ROWS_WG * XS_LDW];   // 34,816 B
    __shared__ float wd[64 * 16];            //  4,096 B

    const int tid = threadIdx.x;
    const int bx  = blockIdx.x;
    const int cj  = bx % CHUNKS;             // chunk id 0..35 (wg-uniform)
    const int rt  = bx / CHUNKS;             // row tile 0..127
    const int row_base = rt * ROWS_WG;

    // ---- densify this chunk's weights into wd[64][16] (k-major) ----
    if (cj < 4) {                            // group 1: 4 blocks of 16->4
        const int wbase = cj * 256;
        #pragma unroll
        for (int i = 0; i < 8; ++i) {
            const int e = tid + i * 128, k = e >> 4, c = e & 15, b = k >> 4;
            wd[e] = ((c >> 2) == b)
                  ? w[wbase + b * 64 + ((k & 15) << 2) + (c & 3)] : 0.0f;
        }
    } else if (cj < 20) {                    // group 2: 2 blocks of 32->8
        const int wbase = 1024 + (cj - 4) * 512;
        #pragma unroll
        for (int i = 0; i < 8; ++i) {
            const int e = tid + i * 128, k = e >> 4, c = e & 15, b = k >> 5;
            wd[e] = ((c >> 3) == b)
                  ? w[wbase + b * 256 + ((k & 31) << 3) + (c & 7)] : 0.0f;
        }
    } else {                                 // group 3: 1 dense 64->16 block
        const int wbase = 9216 + (cj - 20) * 1024;
        #pragma unroll
        for (int i = 0; i < 8; ++i) {
            const int e = tid + i * 128;
            wd[e] = w[wbase + e];
        }
    }

    // ---- stage x tile: 128 rows x 64 cols, coalesced float4 ----
    const float* __restrict__ xsrc = x + (size_t)row_base * IN_DIM + cj * 64;
    #pragma unroll
    for (int i = 0; i < 16; ++i) {
        const int f = tid + i * 128, r = f >> 4, c = (f & 15) << 2;
        const float4 v = *reinterpret_cast<const float4*>(
            xsrc + (size_t)r * IN_DIM + c);
        *reinterpret_cast<float4*>(&xs[r * XS_LDW + c]) = v;
    }
    __syncthreads();

    // ---- compute: wave wv -> 64x16 tile; lane -> 4 rows x 4 cols ----
    const int wv   = tid >> 6;
    const int lane = tid & 63;
    const int rq   = lane & 15;              // row within tile (stride-16 quads)
    const int cq   = lane >> 4;              // col quad 0..3
    const int wb   = cq << 2;                // out-col base within chunk
    const int row0 = wv * 64 + rq;           // first of 4 rows {row0 + 16*i}

    const float* xp0 = &xs[(row0 +  0) * XS_LDW];
    const float* xp1 = &xs[(row0 + 16) * XS_LDW];
    const float* xp2 = &xs[(row0 + 32) * XS_LDW];
    const float* xp3 = &xs[(row0 + 48) * XS_LDW];

    const float4 bv = *reinterpret_cast<const float4*>(bias + cj * 16 + wb);
    float4 a0 = bv, a1 = bv, a2 = bv, a3 = bv;

    // lane's 4 cols sit in exactly one diagonal block -> loop only its k-range
    if (cj < 4) {                            // block = cq, k in [16cq, 16cq+16)
        const int kb = cq << 4;
        tile_fma<4>(xp0 + kb, xp1 + kb, xp2 + kb, xp3 + kb,
                    &wd[wb + (kb << 4)], a0, a1, a2, a3);
    } else if (cj < 20) {                    // block = cq>>1, k in [32b, 32b+32)
        const int kb = (cq >> 1) << 5;
        tile_fma<8>(xp0 + kb, xp1 + kb, xp2 + kb, xp3 + kb,
                    &wd[wb + (kb << 4)], a0, a1, a2, a3);
    } else {                                 // dense 64x16
        tile_fma<16>(xp0, xp1, xp2, xp3, &wd[wb], a0, a1, a2, a3);
    }

    // ---- store: 4 float4 per lane; 4 cq lanes cover 64 B per row ----
    float* __restrict__ op =
        out + (size_t)(row_base + row0) * OUT_DIM + cj * 16 + wb;
    *reinterpret_cast<float4*>(op)                = a0;
    *reinterpret_cast<float4*>(op + 16 * OUT_DIM) = a1;
    *reinterpret_cast<float4*>(op + 32 * OUT_DIM) = a2;
    *reinterpret_cast<float4*>(op + 48 * OUT_DIM) = a3;
}

extern "C" void kernel_launch(void* const* d_in, const int* in_sizes, int n_in,
                              void* d_out, int out_size, void* d_ws, size_t ws_size,
                              hipStream_t stream) {
    const float* x    = (const float*)d_in[0];
    const float* w    = (const float*)d_in[1];
    const float* bias = (const float*)d_in[2];
    float* out        = (float*)d_out;

    const int row_tiles = BATCH / ROWS_WG;           // 128
    fused_block_mm<<<dim3(CHUNKS * row_tiles), 128, 0, stream>>>(
        x, w, bias, out);
}

// Round 3
// 228.595 us; speedup vs baseline: 1.0155x; 1.0155x over previous
//
#include <hip/hip_runtime.h>

// TeacherEmbeddingTransform: block-diagonal GEMM, fp32.
//   x: (16384, 2304), weight: (25600,1) flat, bias: (576,), out: (16384, 576)
//   Blocks: 16x [16->4], 32x [32->8], 16x [64->16]
// Memory-bound: 151 MB read + 38 MB write => ~30 us floor at 6.3 TB/s.
//
// v3: scalar-path weights + sparsity k-loops + high occupancy.
//   - 36 chunks of 64 in-cols -> 16 out-cols (4x 16->4 | 2x 32->8 | 1x 64->16)
//   - wg = 256 thr (4 waves), 64 rows. lane = row; wave wv -> out cols
//     cj*16+4wv..+3. Those 4 cols live in ONE diagonal block -> k-loop spans
//     only that block (NK quads = 4 / 8 / 16), no zero-padded FMAs.
//   - WEIGHTS NEVER TOUCH LDS: per wave the 4 cols' weights are wave-uniform.
//     readfirstlane forces the base offset into an SGPR -> compiler emits
//     s_load_dwordx4 (w[k][c0..c0+3] is 16B-contiguous in the native layout,
//     stride CH floats per k). Kills the wd densify (global+LDS+sync cost)
//     and 4 of the 5 LDS reads per 16 FMAs. FMA = v_fmac_f32 v,s,v.
//   - x staged once: 64x64 tile, XS_LDW=68 keeps ds b128 read/write at the
//     8-cycle data floor (consecutive dwords -> consecutive banks).
//   - LDS 17.4 KB -> 8 wg/CU = 32 waves/CU (vs v2's 8): full latency hiding.
// Budget/CU: HBM ~30 us, LDS ~10 us, VALU ~7 us -> HBM-bound ~33 us kernel.

#define BATCH   16384
#define IN_DIM  2304
#define OUT_DIM 576
#define CHUNKS  36
#define XS_LDW  68   // 64 + 4 pad; b128 rows hit the 8-cyc floor, conflict-free
#define ROWS_WG 64

// NK = k-quads in this block, CH = block's output width (w row stride).
// xrow: lane's x row at the block's k-base. wp: wave-uniform weight base
// (w + block base + c0) -> scalar loads.
template<int NK, int CH>
__device__ __forceinline__ void col_fma(const float* __restrict__ xrow,
                                        const float* __restrict__ wp,
                                        float4& acc)
{
    #pragma unroll
    for (int t = 0; t < NK; ++t) {
        const int k = t << 2;
        const float4 xv = *reinterpret_cast<const float4*>(xrow + k);
        const float4 w0 = *reinterpret_cast<const float4*>(wp + (k + 0) * CH);
        const float4 w1 = *reinterpret_cast<const float4*>(wp + (k + 1) * CH);
        const float4 w2 = *reinterpret_cast<const float4*>(wp + (k + 2) * CH);
        const float4 w3 = *reinterpret_cast<const float4*>(wp + (k + 3) * CH);
        acc.x += xv.x*w0.x + xv.y*w1.x + xv.z*w2.x + xv.w*w3.x;
        acc.y += xv.x*w0.y + xv.y*w1.y + xv.z*w2.y + xv.w*w3.y;
        acc.z += xv.x*w0.z + xv.y*w1.z + xv.z*w2.z + xv.w*w3.z;
        acc.w += xv.x*w0.w + xv.y*w1.w + xv.z*w2.w + xv.w*w3.w;
    }
}

__global__ __launch_bounds__(256) void fused_block_mm(
    const float* __restrict__ x, const float* __restrict__ w,
    const float* __restrict__ bias, float* __restrict__ out)
{
    __shared__ float xs[ROWS_WG * XS_LDW];   // 17,408 B

    const int tid = threadIdx.x;
    const int bx  = blockIdx.x;
    const int cj  = bx % CHUNKS;             // chunk id 0..35 (wg-uniform)
    const int rt  = bx / CHUNKS;             // row tile 0..255
    const int row_base = rt * ROWS_WG;

    // ---- stage x tile: 64 rows x 64 cols, coalesced float4 ----
    const float* __restrict__ xsrc = x + (size_t)row_base * IN_DIM + cj * 64;
    #pragma unroll
    for (int i = 0; i < 4; ++i) {
        const int f = tid + (i << 8), r = f >> 4, c = (f & 15) << 2;
        *reinterpret_cast<float4*>(&xs[r * XS_LDW + c]) =
            *reinterpret_cast<const float4*>(xsrc + (size_t)r * IN_DIM + c);
    }
    __syncthreads();

    // ---- compute: wave wv -> out cols cj*16+4wv..+3, lane = row ----
    const int wv   = tid >> 6;
    const int lane = tid & 63;
    const int ocol = cj * 16 + (wv << 2);

    float4 acc = *reinterpret_cast<const float4*>(bias + ocol);
    const float* xrow = &xs[lane * XS_LDW];

    if (cj < 4) {
        // group 1: 4 blocks of 16->4; wave's block = wv, k in [16wv, 16wv+16)
        const int woff = __builtin_amdgcn_readfirstlane(cj * 256 + wv * 64);
        col_fma<4, 4>(xrow + (wv << 4), w + woff, acc);
    } else if (cj < 20) {
        // group 2: 2 blocks of 32->8; block = wv>>1, c0 = (wv&1)*4
        const int woff = __builtin_amdgcn_readfirstlane(
            1024 + (cj - 4) * 512 + ((wv >> 1) << 8) + ((wv & 1) << 2));
        col_fma<8, 8>(xrow + ((wv >> 1) << 5), w + woff, acc);
    } else {
        // group 3: 1 dense 64->16 block; c0 = 4wv
        const int woff = __builtin_amdgcn_readfirstlane(
            9216 + (cj - 20) * 1024 + (wv << 2));
        col_fma<16, 16>(xrow, w + woff, acc);
    }

    // ---- store: float4 per lane; 4 waves cover 64 B per row ----
    float* __restrict__ op =
        out + (size_t)(row_base + lane) * OUT_DIM + ocol;
    *reinterpret_cast<float4*>(op) = acc;
}

extern "C" void kernel_launch(void* const* d_in, const int* in_sizes, int n_in,
                              void* d_out, int out_size, void* d_ws, size_t ws_size,
                              hipStream_t stream) {
    const float* x    = (const float*)d_in[0];
    const float* w    = (const float*)d_in[1];
    const float* bias = (const float*)d_in[2];
    float* out        = (float*)d_out;

    const int row_tiles = BATCH / ROWS_WG;           // 256
    fused_block_mm<<<dim3(CHUNKS * row_tiles), 256, 0, stream>>>(
        x, w, bias, out);
}

// Round 6
// 226.030 us; speedup vs baseline: 1.0270x; 1.0113x over previous
//
#include <hip/hip_runtime.h>

// TeacherEmbeddingTransform: block-diagonal GEMM, fp32.
//   x: (16384, 2304), weight: (25600,1) flat, bias: (576,), out: (16384, 576)
//   Blocks: 16x [16->4], 32x [32->8], 16x [64->16]
// Memory-bound: 151 MB read + 38 MB write => ~30 us floor at 6.3 TB/s.
//
// v5 = v3 (proven to pass in R3) + XCD-pairing blockIdx swizzle ONLY.
//   v4 (512-thr chunk-paired wg) hit "container failed twice" twice in a
//   row; rather than keep betting on that binary, the same H2 experiment is
//   re-expressed as a remap of v3's grid: the two wgs that write the two
//   64 B halves of each 128 B out-line (cj=2c / 2c+1, same row tile) are
//   placed 8 apart in blockIdx -> SAME XCD under round-robin dispatch,
//   temporally adjacent -> the full line assembles in one (non-coherent) L2
//   before writeback, eliminating the cross-XCD partial-line tax (if any).
//   Mapping: pair p = rt*18 + (cj>>1), member m = cj&1;
//            bx = ((p>>3)*2 + m)*8 + (p&7)   (bijective on [0, 9216))
//   Inverse: x=bx&7; g=bx>>3; m=g&1; p=(g>>1)*8+x; rt=p/18; cj=2*(p%18)+m.
//   Side benefit: each XCD's x-read stream becomes contiguous 512 B
//   segments (pair members read adjacent 256 B col-ranges of the same rows).
//   Kernel body, wg size, LDS, weight path: byte-identical to v3.
// If this nulls too, every actionable axis is falsified (LDS 4x, VALU
// 1.44x, occupancy 4x, weight path, write locality) -> kernel is at its
// HBM floor and the 2x ~88 us harness fills dominate -> roofline.

#define BATCH   16384
#define IN_DIM  2304
#define OUT_DIM 576
#define CHUNKS  36
#define XS_LDW  68   // 64 + 4 pad; b128 rows hit the 8-cyc floor, conflict-free
#define ROWS_WG 64

// NK = k-quads in this block, CH = block's output width (w row stride).
template<int NK, int CH>
__device__ __forceinline__ void col_fma(const float* __restrict__ xrow,
                                        const float* __restrict__ wp,
                                        float4& acc)
{
    #pragma unroll
    for (int t = 0; t < NK; ++t) {
        const int k = t << 2;
        const float4 xv = *reinterpret_cast<const float4*>(xrow + k);
        const float4 w0 = *reinterpret_cast<const float4*>(wp + (k + 0) * CH);
        const float4 w1 = *reinterpret_cast<const float4*>(wp + (k + 1) * CH);
        const float4 w2 = *reinterpret_cast<const float4*>(wp + (k + 2) * CH);
        const float4 w3 = *reinterpret_cast<const float4*>(wp + (k + 3) * CH);
        acc.x += xv.x*w0.x + xv.y*w1.x + xv.z*w2.x + xv.w*w3.x;
        acc.y += xv.x*w0.y + xv.y*w1.y + xv.z*w2.y + xv.w*w3.y;
        acc.z += xv.x*w0.z + xv.y*w1.z + xv.z*w2.z + xv.w*w3.z;
        acc.w += xv.x*w0.w + xv.y*w1.w + xv.z*w2.w + xv.w*w3.w;
    }
}

__global__ __launch_bounds__(256) void fused_block_mm(
    const float* __restrict__ x, const float* __restrict__ w,
    const float* __restrict__ bias, float* __restrict__ out)
{
    __shared__ float xs[ROWS_WG * XS_LDW];   // 17,408 B

    const int tid = threadIdx.x;
    const int bx  = blockIdx.x;

    // ---- XCD-pairing remap: line-sharing wg pairs land on one XCD ----
    const int xcd = bx & 7;
    const int g   = bx >> 3;
    const int m   = g & 1;                   // pair member (cj parity)
    const int p   = ((g >> 1) << 3) + xcd;   // pair id 0..4607
    const int rt  = p / 18;                  // row tile 0..255
    const int cj  = ((p % 18) << 1) + m;     // chunk id 0..35 (wg-uniform)
    const int row_base = rt * ROWS_WG;

    // ---- stage x tile: 64 rows x 64 cols, coalesced float4 ----
    const float* __restrict__ xsrc = x + (size_t)row_base * IN_DIM + cj * 64;
    #pragma unroll
    for (int i = 0; i < 4; ++i) {
        const int f = tid + (i << 8), r = f >> 4, c = (f & 15) << 2;
        *reinterpret_cast<float4*>(&xs[r * XS_LDW + c]) =
            *reinterpret_cast<const float4*>(xsrc + (size_t)r * IN_DIM + c);
    }
    __syncthreads();

    // ---- compute: wave wv -> out cols cj*16+4wv..+3, lane = row ----
    const int wv   = tid >> 6;
    const int lane = tid & 63;
    const int ocol = cj * 16 + (wv << 2);

    float4 acc = *reinterpret_cast<const float4*>(bias + ocol);
    const float* xrow = &xs[lane * XS_LDW];

    if (cj < 4) {
        // group 1: 4 blocks of 16->4; wave's block = wv, k in [16wv, 16wv+16)
        const int woff = __builtin_amdgcn_readfirstlane(cj * 256 + wv * 64);
        col_fma<4, 4>(xrow + (wv << 4), w + woff, acc);
    } else if (cj < 20) {
        // group 2: 2 blocks of 32->8; block = wv>>1, c0 = (wv&1)*4
        const int woff = __builtin_amdgcn_readfirstlane(
            1024 + (cj - 4) * 512 + ((wv >> 1) << 8) + ((wv & 1) << 2));
        col_fma<8, 8>(xrow + ((wv >> 1) << 5), w + woff, acc);
    } else {
        // group 3: 1 dense 64->16 block; c0 = 4wv
        const int woff = __builtin_amdgcn_readfirstlane(
            9216 + (cj - 20) * 1024 + (wv << 2));
        col_fma<16, 16>(xrow, w + woff, acc);
    }

    // ---- store: float4 per lane; 4 waves cover 64 B per row ----
    float* __restrict__ op =
        out + (size_t)(row_base + lane) * OUT_DIM + ocol;
    *reinterpret_cast<float4*>(op) = acc;
}

extern "C" void kernel_launch(void* const* d_in, const int* in_sizes, int n_in,
                              void* d_out, int out_size, void* d_ws, size_t ws_size,
                              hipStream_t stream) {
    const float* x    = (const float*)d_in[0];
    const float* w    = (const float*)d_in[1];
    const float* bias = (const float*)d_in[2];
    float* out        = (float*)d_out;

    const int row_tiles = BATCH / ROWS_WG;           // 256
    fused_block_mm<<<dim3(CHUNKS * row_tiles), 256, 0, stream>>>(
        x, w, bias, out);
}